// Round 2
// baseline (5726.020 us; speedup 1.0000x reference)
//
#include <hip/hip_runtime.h>

// Problem constants (from reference)
#define NN     50000
#define NFEAT  512
#define HIDD   128
#define NE     1600000

// ---------------------------------------------------------------------------
// COO atomic SpMM, D=128: out[row] += val * dense[col].
// One 32-lane group per edge; float4 gather per lane; 4 fp32 atomics.
// ---------------------------------------------------------------------------
__global__ __launch_bounds__(256) void spmm_atomic_kernel(
    const int* __restrict__ row, const int* __restrict__ col,
    const float* __restrict__ val, const float* __restrict__ dense,
    float* __restrict__ out) {
  int e = blockIdx.x * 8 + (threadIdx.x >> 5);
  if (e >= NE) return;
  int lane = threadIdx.x & 31;
  int r = row[e], c = col[e];
  float v = val[e];
  const float4* dense4 = (const float4*)dense;
  float4 d = dense4[(size_t)c * 32 + lane];
  float* o = out + (size_t)r * 128 + lane * 4;
  atomicAdd(o + 0, v * d.x);
  atomicAdd(o + 1, v * d.y);
  atomicAdd(o + 2, v * d.z);
  atomicAdd(o + 3, v * d.w);
}

// ---------------------------------------------------------------------------
// buf = relu(buf + bias), in-place over [N,128] (float4 granularity)
// ---------------------------------------------------------------------------
__global__ __launch_bounds__(256) void bias_relu_kernel(
    float* __restrict__ buf, const float* __restrict__ bias) {
  int i = blockIdx.x * blockDim.x + threadIdx.x;  // float4 index
  if (i >= NN * 32) return;
  float4 t = ((float4*)buf)[i];
  float4 b = ((const float4*)bias)[i & 31];
  t.x = fmaxf(t.x + b.x, 0.f);
  t.y = fmaxf(t.y + b.y, 0.f);
  t.z = fmaxf(t.z + b.z, 0.f);
  t.w = fmaxf(t.w + b.w, 0.f);
  ((float4*)buf)[i] = t;
}

// ---------------------------------------------------------------------------
// fp32 tiled GEMM: C[M,Ncols] = A[M,K] @ B[K,Ncols]  (+bias, relu if EPI)
// BM=64, BN=128, BK=32, 256 threads, 8x4 micro-tile per thread.
// ---------------------------------------------------------------------------
template <int K, bool EPI>
__global__ __launch_bounds__(256) void gemm_kernel(
    const float* __restrict__ A, const float* __restrict__ B,
    const float* __restrict__ bias, float* __restrict__ C,
    int M, int Ncols) {
  constexpr int BM = 64, BN = 128, BK = 32;
  __shared__ __align__(16) float As[BK][BM + 4];  // transposed A tile
  __shared__ __align__(16) float Bs[BK][BN];
  int tid = threadIdx.x;
  int tx = tid & 31;   // col group (4 cols)
  int ty = tid >> 5;   // row group (8 rows)
  int rowBase = blockIdx.x * BM;
  int colBase = blockIdx.y * BN;
  float acc[8][4] = {};
  for (int kb = 0; kb < K; kb += BK) {
    // A tile: 64x32 floats = 512 float4
#pragma unroll
    for (int s = 0; s < 2; ++s) {
      int q = tid + s * 256;
      int r = q >> 3;
      int kq = (q & 7) * 4;
      float4 v = make_float4(0.f, 0.f, 0.f, 0.f);
      int gr = rowBase + r;
      if (gr < M) v = *(const float4*)(A + (size_t)gr * K + kb + kq);
      As[kq + 0][r] = v.x;
      As[kq + 1][r] = v.y;
      As[kq + 2][r] = v.z;
      As[kq + 3][r] = v.w;
    }
    // B tile: 32x128 floats = 1024 float4
#pragma unroll
    for (int s = 0; s < 4; ++s) {
      int q = tid + s * 256;
      int kr = q >> 5;
      int cq = (q & 31) * 4;
      float4 v = *(const float4*)(B + (size_t)(kb + kr) * Ncols + colBase + cq);
      *(float4*)&Bs[kr][cq] = v;
    }
    __syncthreads();
#pragma unroll
    for (int kk = 0; kk < BK; ++kk) {
      float4 a0 = *(const float4*)&As[kk][ty * 8];
      float4 a1 = *(const float4*)&As[kk][ty * 8 + 4];
      float4 b0 = *(const float4*)&Bs[kk][tx * 4];
      float av[8] = {a0.x, a0.y, a0.z, a0.w, a1.x, a1.y, a1.z, a1.w};
      float bv[4] = {b0.x, b0.y, b0.z, b0.w};
#pragma unroll
      for (int i = 0; i < 8; ++i)
#pragma unroll
        for (int j = 0; j < 4; ++j)
          acc[i][j] = fmaf(av[i], bv[j], acc[i][j]);
    }
    __syncthreads();
  }
#pragma unroll
  for (int i = 0; i < 8; ++i) {
    int gr = rowBase + ty * 8 + i;
    if (gr < M) {
      int gc = colBase + tx * 4;
      float4 o;
      o.x = acc[i][0]; o.y = acc[i][1]; o.z = acc[i][2]; o.w = acc[i][3];
      if (EPI) {
        o.x = fmaxf(o.x + bias[gc + 0], 0.f);
        o.y = fmaxf(o.y + bias[gc + 1], 0.f);
        o.z = fmaxf(o.z + bias[gc + 2], 0.f);
        o.w = fmaxf(o.w + bias[gc + 3], 0.f);
      }
      *(float4*)(C + (size_t)gr * Ncols + gc) = o;
    }
  }
}

// ---------------------------------------------------------------------------
extern "C" void kernel_launch(void* const* d_in, const int* in_sizes, int n_in,
                              void* d_out, int out_size, void* d_ws, size_t ws_size,
                              hipStream_t stream) {
  const float* x        = (const float*)d_in[0];
  const int*   adj_row  = (const int*)d_in[1];
  const int*   adj_col  = (const int*)d_in[2];
  const float* adj_val  = (const float*)d_in[3];
  const int*   ainv_row = (const int*)d_in[4];
  const int*   ainv_col = (const int*)d_in[5];
  const float* ainv_val = (const float*)d_in[6];
  const float* W1       = (const float*)d_in[7];
  const float* b1       = (const float*)d_in[8];
  const float* W2       = (const float*)d_in[9];
  const float* b2       = (const float*)d_in[10];

  float* out = (float*)d_out;                    // [N,512]
  float* emb = out + (size_t)NN * NFEAT;         // [N,128]

  // Workspace carve: H0 [N,128] + T [N,128] = 51.2 MB
  float* H0 = (float*)d_ws;
  float* T  = H0 + (size_t)NN * HIDD;

  // Zero the two accumulators (emb accumulates A@H0; T accumulates A_inv@emb)
  hipMemsetAsync(emb, 0, (size_t)NN * HIDD * sizeof(float), stream);
  hipMemsetAsync(T,   0, (size_t)NN * HIDD * sizeof(float), stream);

  // ---- H0 = X @ W1 ----
  gemm_kernel<NFEAT, false><<<dim3((NN + 63) / 64, 1), 256, 0, stream>>>(
      x, W1, nullptr, H0, NN, HIDD);

  // ---- emb += A @ H0 (atomic COO SpMM) ----
  spmm_atomic_kernel<<<NE / 8, 256, 0, stream>>>(
      adj_row, adj_col, adj_val, H0, emb);

  // ---- emb = relu(emb + b1) ----
  bias_relu_kernel<<<(NN * 32 + 255) / 256, 256, 0, stream>>>(emb, b1);

  // ---- T += A_inv @ emb (atomic COO SpMM; reassociated (A_inv@h)@W2) ----
  spmm_atomic_kernel<<<NE / 8, 256, 0, stream>>>(
      ainv_row, ainv_col, ainv_val, emb, T);

  // ---- out = relu(T @ W2 + b2) ----
  gemm_kernel<HIDD, true><<<dim3((NN + 63) / 64, 4), 256, 0, stream>>>(
      T, W2, b2, out, NN, NFEAT);
}

// Round 3
// 994.418 us; speedup vs baseline: 5.7582x; 5.7582x over previous
//
#include <hip/hip_runtime.h>

// Problem constants (from reference)
#define NN     50000
#define NFEAT  512
#define HIDD   128
#define NE     1600000
#define NB     ((NN + 255) / 256)   // 196 blocks for per-node arrays

// ---------------------------------------------------------------------------
// Histogram: counts[row[i]]++  (int atomics, L2-side, cheap)
// ---------------------------------------------------------------------------
__global__ __launch_bounds__(256) void hist_kernel(
    const int* __restrict__ row, int* __restrict__ counts, int e) {
  int i = blockIdx.x * blockDim.x + threadIdx.x;
  if (i < e) atomicAdd(&counts[row[i]], 1);
}

// ---------------------------------------------------------------------------
// Scan phase 1: per-block sums of counts -> bsum[block]
// ---------------------------------------------------------------------------
__global__ __launch_bounds__(256) void block_sum_kernel(
    const int* __restrict__ counts, int* __restrict__ bsum, int n) {
  __shared__ int ws[4];
  int i = blockIdx.x * 256 + threadIdx.x;
  int lane = threadIdx.x & 63, wid = threadIdx.x >> 6;
  int v = (i < n) ? counts[i] : 0;
#pragma unroll
  for (int off = 32; off > 0; off >>= 1) v += __shfl_down(v, off, 64);
  if (lane == 0) ws[wid] = v;
  __syncthreads();
  if (threadIdx.x == 0) bsum[blockIdx.x] = ws[0] + ws[1] + ws[2] + ws[3];
}

// ---------------------------------------------------------------------------
// Scan phase 2: single block, exclusive-scan nb partials in place;
// write grand total to rowptr[NN].
// ---------------------------------------------------------------------------
__global__ __launch_bounds__(256) void scan_partials_kernel(
    int* __restrict__ bsum, int* __restrict__ rowptr, int nb, int nfull) {
  __shared__ int ws[4];
  int t = threadIdx.x;
  int lane = t & 63, wid = t >> 6;
  int v = (t < nb) ? bsum[t] : 0;
  int incl = v;
#pragma unroll
  for (int off = 1; off < 64; off <<= 1) {
    int u = __shfl_up(incl, off, 64);
    if (lane >= off) incl += u;
  }
  if (lane == 63) ws[wid] = incl;
  __syncthreads();
  int wprefix = 0;
  for (int w = 0; w < wid; ++w) wprefix += ws[w];
  incl += wprefix;
  if (t < nb) bsum[t] = incl - v;          // exclusive
  if (t == nb - 1) rowptr[nfull] = incl;   // grand total
}

// ---------------------------------------------------------------------------
// Scan phase 3: in-place exclusive scan of counts using bsum offsets.
// counts[i] (a count) -> exclusive offset; also duplicated into rowptr[i].
// counts buffer then serves as the scatter write-pointer.
// ---------------------------------------------------------------------------
__global__ __launch_bounds__(256) void scan_apply_kernel(
    int* __restrict__ counts, const int* __restrict__ bsum,
    int* __restrict__ rowptr, int n) {
  __shared__ int ws[4];
  int i = blockIdx.x * 256 + threadIdx.x;
  int lane = threadIdx.x & 63, wid = threadIdx.x >> 6;
  int v = (i < n) ? counts[i] : 0;
  int incl = v;
#pragma unroll
  for (int off = 1; off < 64; off <<= 1) {
    int u = __shfl_up(incl, off, 64);
    if (lane >= off) incl += u;
  }
  if (lane == 63) ws[wid] = incl;
  __syncthreads();
  int wprefix = 0;
  for (int w = 0; w < wid; ++w) wprefix += ws[w];
  int excl = bsum[blockIdx.x] + wprefix + (incl - v);
  if (i < n) { rowptr[i] = excl; counts[i] = excl; }
}

// ---------------------------------------------------------------------------
// Packed scatter: one 8B store per edge {col, val-bits}
// ---------------------------------------------------------------------------
__global__ __launch_bounds__(256) void scatter_kernel(
    const int* __restrict__ row, const int* __restrict__ col,
    const float* __restrict__ val, int* __restrict__ wptr,
    int2* __restrict__ pairs, int e) {
  int i = blockIdx.x * blockDim.x + threadIdx.x;
  if (i < e) {
    int p = atomicAdd(&wptr[row[i]], 1);
    pairs[p] = make_int2(col[i], __float_as_int(val[i]));
  }
}

// ---------------------------------------------------------------------------
// CSR SpMM, D=128. One 32-lane group per row, float4 per lane.
// Optional fused bias+relu epilogue.
// ---------------------------------------------------------------------------
template <bool EPI>
__global__ __launch_bounds__(256) void spmm_kernel(
    const int* __restrict__ rowptr, const int2* __restrict__ pairs,
    const float* __restrict__ dense, const float* __restrict__ bias,
    float* __restrict__ out, int n) {
  int r = blockIdx.x * 8 + (threadIdx.x >> 5);
  if (r >= n) return;
  int c4 = (threadIdx.x & 31);  // float4 index within row
  const float4* dense4 = (const float4*)dense;
  int s = rowptr[r], e = rowptr[r + 1];
  float4 acc = make_float4(0.f, 0.f, 0.f, 0.f);
  for (int j = s; j < e; ++j) {
    int2 ev = pairs[j];
    int ci = ev.x;
    float v = __int_as_float(ev.y);
    float4 d = dense4[(size_t)ci * 32 + c4];
    acc.x = fmaf(v, d.x, acc.x);
    acc.y = fmaf(v, d.y, acc.y);
    acc.z = fmaf(v, d.z, acc.z);
    acc.w = fmaf(v, d.w, acc.w);
  }
  if (EPI) {
    float4 b = ((const float4*)bias)[c4];
    acc.x = fmaxf(acc.x + b.x, 0.f);
    acc.y = fmaxf(acc.y + b.y, 0.f);
    acc.z = fmaxf(acc.z + b.z, 0.f);
    acc.w = fmaxf(acc.w + b.w, 0.f);
  }
  *(float4*)(out + (size_t)r * 128 + c4 * 4) = acc;
}

// ---------------------------------------------------------------------------
// fp32 tiled GEMM: C[M,Ncols] = A[M,K] @ B[K,Ncols]  (+bias, relu if EPI)
// BM=64, BN=128, BK=32, 256 threads, 8x4 micro-tile per thread.
// ---------------------------------------------------------------------------
template <int K, bool EPI>
__global__ __launch_bounds__(256) void gemm_kernel(
    const float* __restrict__ A, const float* __restrict__ B,
    const float* __restrict__ bias, float* __restrict__ C,
    int M, int Ncols) {
  constexpr int BM = 64, BN = 128, BK = 32;
  __shared__ __align__(16) float As[BK][BM + 4];  // transposed A tile
  __shared__ __align__(16) float Bs[BK][BN];
  int tid = threadIdx.x;
  int tx = tid & 31;   // col group (4 cols)
  int ty = tid >> 5;   // row group (8 rows)
  int rowBase = blockIdx.x * BM;
  int colBase = blockIdx.y * BN;
  float acc[8][4] = {};
  for (int kb = 0; kb < K; kb += BK) {
#pragma unroll
    for (int s = 0; s < 2; ++s) {
      int q = tid + s * 256;
      int r = q >> 3;
      int kq = (q & 7) * 4;
      float4 v = make_float4(0.f, 0.f, 0.f, 0.f);
      int gr = rowBase + r;
      if (gr < M) v = *(const float4*)(A + (size_t)gr * K + kb + kq);
      As[kq + 0][r] = v.x;
      As[kq + 1][r] = v.y;
      As[kq + 2][r] = v.z;
      As[kq + 3][r] = v.w;
    }
#pragma unroll
    for (int s = 0; s < 4; ++s) {
      int q = tid + s * 256;
      int kr = q >> 5;
      int cq = (q & 31) * 4;
      float4 v = *(const float4*)(B + (size_t)(kb + kr) * Ncols + colBase + cq);
      *(float4*)&Bs[kr][cq] = v;
    }
    __syncthreads();
#pragma unroll
    for (int kk = 0; kk < BK; ++kk) {
      float4 a0 = *(const float4*)&As[kk][ty * 8];
      float4 a1 = *(const float4*)&As[kk][ty * 8 + 4];
      float4 b0 = *(const float4*)&Bs[kk][tx * 4];
      float av[8] = {a0.x, a0.y, a0.z, a0.w, a1.x, a1.y, a1.z, a1.w};
      float bv[4] = {b0.x, b0.y, b0.z, b0.w};
#pragma unroll
      for (int i = 0; i < 8; ++i)
#pragma unroll
        for (int j = 0; j < 4; ++j)
          acc[i][j] = fmaf(av[i], bv[j], acc[i][j]);
    }
    __syncthreads();
  }
#pragma unroll
  for (int i = 0; i < 8; ++i) {
    int gr = rowBase + ty * 8 + i;
    if (gr < M) {
      int gc = colBase + tx * 4;
      float4 o;
      o.x = acc[i][0]; o.y = acc[i][1]; o.z = acc[i][2]; o.w = acc[i][3];
      if (EPI) {
        o.x = fmaxf(o.x + bias[gc + 0], 0.f);
        o.y = fmaxf(o.y + bias[gc + 1], 0.f);
        o.z = fmaxf(o.z + bias[gc + 2], 0.f);
        o.w = fmaxf(o.w + bias[gc + 3], 0.f);
      }
      *(float4*)(C + (size_t)gr * Ncols + gc) = o;
    }
  }
}

// ---------------------------------------------------------------------------
extern "C" void kernel_launch(void* const* d_in, const int* in_sizes, int n_in,
                              void* d_out, int out_size, void* d_ws, size_t ws_size,
                              hipStream_t stream) {
  const float* x        = (const float*)d_in[0];
  const int*   adj_row  = (const int*)d_in[1];
  const int*   adj_col  = (const int*)d_in[2];
  const float* adj_val  = (const float*)d_in[3];
  const int*   ainv_row = (const int*)d_in[4];
  const int*   ainv_col = (const int*)d_in[5];
  const float* ainv_val = (const float*)d_in[6];
  const float* W1       = (const float*)d_in[7];
  const float* b1       = (const float*)d_in[8];
  const float* W2       = (const float*)d_in[9];
  const float* b2       = (const float*)d_in[10];

  float* out = (float*)d_out;                    // [N,512]
  float* emb = out + (size_t)NN * NFEAT;         // [N,128]

  // Workspace carve (~52 MB)
  float* H0       = (float*)d_ws;                // [N,128]; later aliased as T
  int*   rowptr_a = (int*)(H0 + (size_t)NN * HIDD);
  int*   rowptr_b = rowptr_a + 50004;
  int*   wptr_a   = rowptr_b + 50004;            // histogram -> write ptr
  int*   wptr_b   = wptr_a + 50004;
  int*   bsum_a   = wptr_b + 50004;              // NB=196 partials
  int*   bsum_b   = bsum_a + 256;
  int2*  pairs_a  = (int2*)(bsum_b + 256);       // NE packed {col,val}
  int2*  pairs_b  = pairs_a + NE;
  float* T        = H0;  // alias: H0 dead by the time T is written

  // ---- CSR build for both graphs ----
  hipMemsetAsync(wptr_a, 0, NN * sizeof(int), stream);
  hipMemsetAsync(wptr_b, 0, NN * sizeof(int), stream);
  hist_kernel<<<NE / 256, 256, 0, stream>>>(adj_row, wptr_a, NE);
  hist_kernel<<<NE / 256, 256, 0, stream>>>(ainv_row, wptr_b, NE);
  block_sum_kernel<<<NB, 256, 0, stream>>>(wptr_a, bsum_a, NN);
  block_sum_kernel<<<NB, 256, 0, stream>>>(wptr_b, bsum_b, NN);
  scan_partials_kernel<<<1, 256, 0, stream>>>(bsum_a, rowptr_a, NB, NN);
  scan_partials_kernel<<<1, 256, 0, stream>>>(bsum_b, rowptr_b, NB, NN);
  scan_apply_kernel<<<NB, 256, 0, stream>>>(wptr_a, bsum_a, rowptr_a, NN);
  scan_apply_kernel<<<NB, 256, 0, stream>>>(wptr_b, bsum_b, rowptr_b, NN);
  scatter_kernel<<<NE / 256, 256, 0, stream>>>(adj_row, adj_col, adj_val,
                                               wptr_a, pairs_a, NE);
  scatter_kernel<<<NE / 256, 256, 0, stream>>>(ainv_row, ainv_col, ainv_val,
                                               wptr_b, pairs_b, NE);

  // ---- H0 = X @ W1 ----
  gemm_kernel<NFEAT, false><<<dim3((NN + 63) / 64, 1), 256, 0, stream>>>(
      x, W1, nullptr, H0, NN, HIDD);

  // ---- emb = relu(A @ H0 + b1) ----
  spmm_kernel<true><<<(NN + 7) / 8, 256, 0, stream>>>(
      rowptr_a, pairs_a, H0, b1, emb, NN);

  // ---- T = A_inv @ emb  (reassociated: (A_inv @ h) @ W2) ----
  spmm_kernel<false><<<(NN + 7) / 8, 256, 0, stream>>>(
      rowptr_b, pairs_b, emb, nullptr, T, NN);

  // ---- out = relu(T @ W2 + b2) ----
  gemm_kernel<HIDD, true><<<dim3((NN + 63) / 64, 4), 256, 0, stream>>>(
      T, W2, b2, out, NN, NFEAT);
}

// Round 4
// 908.493 us; speedup vs baseline: 6.3028x; 1.0946x over previous
//
#include <hip/hip_runtime.h>

// Problem constants (from reference)
#define NN     50000
#define NFEAT  512
#define HIDD   128
#define NE     1600000
#define NB     ((NN + 255) / 256)   // 196 blocks for per-node arrays
#define NPART  8                    // row partitions ~ XCDs
#define RPP    (NN / NPART)         // 6250 rows per partition

// ---------------------------------------------------------------------------
// Histogram: counts[row[i]]++  (int atomics)
// ---------------------------------------------------------------------------
__global__ __launch_bounds__(256) void hist_kernel(
    const int* __restrict__ row, int* __restrict__ counts, int e) {
  int i = blockIdx.x * blockDim.x + threadIdx.x;
  if (i < e) atomicAdd(&counts[row[i]], 1);
}

// ---------------------------------------------------------------------------
// Scan phase 1: per-block sums of counts -> bsum[block]
// ---------------------------------------------------------------------------
__global__ __launch_bounds__(256) void block_sum_kernel(
    const int* __restrict__ counts, int* __restrict__ bsum, int n) {
  __shared__ int ws[4];
  int i = blockIdx.x * 256 + threadIdx.x;
  int lane = threadIdx.x & 63, wid = threadIdx.x >> 6;
  int v = (i < n) ? counts[i] : 0;
#pragma unroll
  for (int off = 32; off > 0; off >>= 1) v += __shfl_down(v, off, 64);
  if (lane == 0) ws[wid] = v;
  __syncthreads();
  if (threadIdx.x == 0) bsum[blockIdx.x] = ws[0] + ws[1] + ws[2] + ws[3];
}

// ---------------------------------------------------------------------------
// Scan phase 2: single block, exclusive-scan nb partials in place;
// write grand total to rowptr[NN].
// ---------------------------------------------------------------------------
__global__ __launch_bounds__(256) void scan_partials_kernel(
    int* __restrict__ bsum, int* __restrict__ rowptr, int nb, int nfull) {
  __shared__ int ws[4];
  int t = threadIdx.x;
  int lane = t & 63, wid = t >> 6;
  int v = (t < nb) ? bsum[t] : 0;
  int incl = v;
#pragma unroll
  for (int off = 1; off < 64; off <<= 1) {
    int u = __shfl_up(incl, off, 64);
    if (lane >= off) incl += u;
  }
  if (lane == 63) ws[wid] = incl;
  __syncthreads();
  int wprefix = 0;
  for (int w = 0; w < wid; ++w) wprefix += ws[w];
  incl += wprefix;
  if (t < nb) bsum[t] = incl - v;          // exclusive
  if (t == nb - 1) rowptr[nfull] = incl;   // grand total
}

// ---------------------------------------------------------------------------
// Scan phase 3: in-place exclusive scan of counts using bsum offsets.
// counts[i] -> exclusive offset; duplicated into rowptr[i].
// counts buffer then serves as the scatter write-pointer.
// ---------------------------------------------------------------------------
__global__ __launch_bounds__(256) void scan_apply_kernel(
    int* __restrict__ counts, const int* __restrict__ bsum,
    int* __restrict__ rowptr, int n) {
  __shared__ int ws[4];
  int i = blockIdx.x * 256 + threadIdx.x;
  int lane = threadIdx.x & 63, wid = threadIdx.x >> 6;
  int v = (i < n) ? counts[i] : 0;
  int incl = v;
#pragma unroll
  for (int off = 1; off < 64; off <<= 1) {
    int u = __shfl_up(incl, off, 64);
    if (lane >= off) incl += u;
  }
  if (lane == 63) ws[wid] = incl;
  __syncthreads();
  int wprefix = 0;
  for (int w = 0; w < wid; ++w) wprefix += ws[w];
  int excl = bsum[blockIdx.x] + wprefix + (incl - v);
  if (i < n) { rowptr[i] = excl; counts[i] = excl; }
}

// ---------------------------------------------------------------------------
// XCD-partitioned packed scatter. Block handles only rows in partition
// blockIdx%8; under the round-robin blockIdx->XCD swizzle all stores to a
// partition's 1.6 MB destination slice come from ONE XCD's L2, so the ~32
// edges of a row (4 sectors) merge before write-back. Row array is re-read
// 8x but served by the shared L3.
// ---------------------------------------------------------------------------
__global__ __launch_bounds__(256) void scatter_part_kernel(
    const int* __restrict__ row, const int* __restrict__ col,
    const float* __restrict__ val, int* __restrict__ wptr,
    int2* __restrict__ pairs, int e) {
  int part = blockIdx.x & (NPART - 1);
  int q    = blockIdx.x >> 3;
  int Q    = gridDim.x >> 3;
  int lo = part * RPP, hi = lo + RPP;
  for (int i = q * 256 + threadIdx.x; i < e; i += Q * 256) {
    int r = row[i];
    if (r >= lo && r < hi) {
      int p = atomicAdd(&wptr[r], 1);
      pairs[p] = make_int2(col[i], __float_as_int(val[i]));
    }
  }
}

// ---------------------------------------------------------------------------
// CSR SpMM, D=128. One 32-lane group per row, float4 per lane.
// Optional fused bias+relu epilogue.
// ---------------------------------------------------------------------------
template <bool EPI>
__global__ __launch_bounds__(256) void spmm_kernel(
    const int* __restrict__ rowptr, const int2* __restrict__ pairs,
    const float* __restrict__ dense, const float* __restrict__ bias,
    float* __restrict__ out, int n) {
  int r = blockIdx.x * 8 + (threadIdx.x >> 5);
  if (r >= n) return;
  int c4 = (threadIdx.x & 31);  // float4 index within row
  const float4* dense4 = (const float4*)dense;
  int s = rowptr[r], e = rowptr[r + 1];
  float4 acc = make_float4(0.f, 0.f, 0.f, 0.f);
  for (int j = s; j < e; ++j) {
    int2 ev = pairs[j];
    int ci = ev.x;
    float v = __int_as_float(ev.y);
    float4 d = dense4[(size_t)ci * 32 + c4];
    acc.x = fmaf(v, d.x, acc.x);
    acc.y = fmaf(v, d.y, acc.y);
    acc.z = fmaf(v, d.z, acc.z);
    acc.w = fmaf(v, d.w, acc.w);
  }
  if (EPI) {
    float4 b = ((const float4*)bias)[c4];
    acc.x = fmaxf(acc.x + b.x, 0.f);
    acc.y = fmaxf(acc.y + b.y, 0.f);
    acc.z = fmaxf(acc.z + b.z, 0.f);
    acc.w = fmaxf(acc.w + b.w, 0.f);
  }
  *(float4*)(out + (size_t)r * 128 + c4 * 4) = acc;
}

// ---------------------------------------------------------------------------
// fp32 tiled GEMM: C[M,Ncols] = A[M,K] @ B[K,Ncols]  (+bias, relu if EPI)
// BM=64, BN=128, BK=32, 256 threads, 8x4 micro-tile per thread.
// ---------------------------------------------------------------------------
template <int K, bool EPI>
__global__ __launch_bounds__(256) void gemm_kernel(
    const float* __restrict__ A, const float* __restrict__ B,
    const float* __restrict__ bias, float* __restrict__ C,
    int M, int Ncols) {
  constexpr int BM = 64, BN = 128, BK = 32;
  __shared__ __align__(16) float As[BK][BM + 4];  // transposed A tile
  __shared__ __align__(16) float Bs[BK][BN];
  int tid = threadIdx.x;
  int tx = tid & 31;   // col group (4 cols)
  int ty = tid >> 5;   // row group (8 rows)
  int rowBase = blockIdx.x * BM;
  int colBase = blockIdx.y * BN;
  float acc[8][4] = {};
  for (int kb = 0; kb < K; kb += BK) {
#pragma unroll
    for (int s = 0; s < 2; ++s) {
      int q = tid + s * 256;
      int r = q >> 3;
      int kq = (q & 7) * 4;
      float4 v = make_float4(0.f, 0.f, 0.f, 0.f);
      int gr = rowBase + r;
      if (gr < M) v = *(const float4*)(A + (size_t)gr * K + kb + kq);
      As[kq + 0][r] = v.x;
      As[kq + 1][r] = v.y;
      As[kq + 2][r] = v.z;
      As[kq + 3][r] = v.w;
    }
#pragma unroll
    for (int s = 0; s < 4; ++s) {
      int q = tid + s * 256;
      int kr = q >> 5;
      int cq = (q & 31) * 4;
      float4 v = *(const float4*)(B + (size_t)(kb + kr) * Ncols + colBase + cq);
      *(float4*)&Bs[kr][cq] = v;
    }
    __syncthreads();
#pragma unroll
    for (int kk = 0; kk < BK; ++kk) {
      float4 a0 = *(const float4*)&As[kk][ty * 8];
      float4 a1 = *(const float4*)&As[kk][ty * 8 + 4];
      float4 b0 = *(const float4*)&Bs[kk][tx * 4];
      float av[8] = {a0.x, a0.y, a0.z, a0.w, a1.x, a1.y, a1.z, a1.w};
      float bv[4] = {b0.x, b0.y, b0.z, b0.w};
#pragma unroll
      for (int i = 0; i < 8; ++i)
#pragma unroll
        for (int j = 0; j < 4; ++j)
          acc[i][j] = fmaf(av[i], bv[j], acc[i][j]);
    }
    __syncthreads();
  }
#pragma unroll
  for (int i = 0; i < 8; ++i) {
    int gr = rowBase + ty * 8 + i;
    if (gr < M) {
      int gc = colBase + tx * 4;
      float4 o;
      o.x = acc[i][0]; o.y = acc[i][1]; o.z = acc[i][2]; o.w = acc[i][3];
      if (EPI) {
        o.x = fmaxf(o.x + bias[gc + 0], 0.f);
        o.y = fmaxf(o.y + bias[gc + 1], 0.f);
        o.z = fmaxf(o.z + bias[gc + 2], 0.f);
        o.w = fmaxf(o.w + bias[gc + 3], 0.f);
      }
      *(float4*)(C + (size_t)gr * Ncols + gc) = o;
    }
  }
}

// ---------------------------------------------------------------------------
extern "C" void kernel_launch(void* const* d_in, const int* in_sizes, int n_in,
                              void* d_out, int out_size, void* d_ws, size_t ws_size,
                              hipStream_t stream) {
  const float* x        = (const float*)d_in[0];
  const int*   adj_row  = (const int*)d_in[1];
  const int*   adj_col  = (const int*)d_in[2];
  const float* adj_val  = (const float*)d_in[3];
  const int*   ainv_row = (const int*)d_in[4];
  const int*   ainv_col = (const int*)d_in[5];
  const float* ainv_val = (const float*)d_in[6];
  const float* W1       = (const float*)d_in[7];
  const float* b1       = (const float*)d_in[8];
  const float* W2       = (const float*)d_in[9];
  const float* b2       = (const float*)d_in[10];

  float* out = (float*)d_out;                    // [N,512]
  float* emb = out + (size_t)NN * NFEAT;         // [N,128]

  // Workspace carve (~52 MB)
  float* H0       = (float*)d_ws;                // [N,128]; later aliased as T
  int*   rowptr_a = (int*)(H0 + (size_t)NN * HIDD);
  int*   rowptr_b = rowptr_a + 50004;
  int*   wptr_a   = rowptr_b + 50004;            // histogram -> write ptr
  int*   wptr_b   = wptr_a + 50004;
  int*   bsum_a   = wptr_b + 50004;              // NB=196 partials
  int*   bsum_b   = bsum_a + 256;
  int2*  pairs_a  = (int2*)(bsum_b + 256);       // NE packed {col,val}
  int2*  pairs_b  = pairs_a + NE;
  float* T        = H0;  // alias: H0 dead by the time T is written

  // ---- CSR build for both graphs ----
  hipMemsetAsync(wptr_a, 0, NN * sizeof(int), stream);
  hipMemsetAsync(wptr_b, 0, NN * sizeof(int), stream);
  hist_kernel<<<NE / 256, 256, 0, stream>>>(adj_row, wptr_a, NE);
  hist_kernel<<<NE / 256, 256, 0, stream>>>(ainv_row, wptr_b, NE);
  block_sum_kernel<<<NB, 256, 0, stream>>>(wptr_a, bsum_a, NN);
  block_sum_kernel<<<NB, 256, 0, stream>>>(wptr_b, bsum_b, NN);
  scan_partials_kernel<<<1, 256, 0, stream>>>(bsum_a, rowptr_a, NB, NN);
  scan_partials_kernel<<<1, 256, 0, stream>>>(bsum_b, rowptr_b, NB, NN);
  scan_apply_kernel<<<NB, 256, 0, stream>>>(wptr_a, bsum_a, rowptr_a, NN);
  scan_apply_kernel<<<NB, 256, 0, stream>>>(wptr_b, bsum_b, rowptr_b, NN);
  scatter_part_kernel<<<2048, 256, 0, stream>>>(adj_row, adj_col, adj_val,
                                                wptr_a, pairs_a, NE);
  scatter_part_kernel<<<2048, 256, 0, stream>>>(ainv_row, ainv_col, ainv_val,
                                                wptr_b, pairs_b, NE);

  // ---- H0 = X @ W1 ----
  gemm_kernel<NFEAT, false><<<dim3((NN + 63) / 64, 1), 256, 0, stream>>>(
      x, W1, nullptr, H0, NN, HIDD);

  // ---- emb = relu(A @ H0 + b1) ----
  spmm_kernel<true><<<(NN + 7) / 8, 256, 0, stream>>>(
      rowptr_a, pairs_a, H0, b1, emb, NN);

  // ---- T = A_inv @ emb  (reassociated: (A_inv @ h) @ W2) ----
  spmm_kernel<false><<<(NN + 7) / 8, 256, 0, stream>>>(
      rowptr_b, pairs_b, emb, nullptr, T, NN);

  // ---- out = relu(T @ W2 + b2) ----
  gemm_kernel<HIDD, true><<<dim3((NN + 63) / 64, 4), 256, 0, stream>>>(
      T, W2, b2, out, NN, NFEAT);
}

// Round 5
// 827.238 us; speedup vs baseline: 6.9219x; 1.0982x over previous
//
#include <hip/hip_runtime.h>

// Problem constants (from reference)
#define NN     50000
#define NFEAT  512
#define HIDD   128
#define NE     1600000
#define NB     ((NN + 255) / 256)   // 196 blocks for per-node arrays
#define NPART  8                    // row partitions ~ XCDs
#define RPP    (NN / NPART)         // 6250 rows per partition

typedef __attribute__((ext_vector_type(8))) short    bf16x8;
typedef __attribute__((ext_vector_type(4))) float    f32x4;
typedef __attribute__((ext_vector_type(4))) unsigned short us4;

__device__ inline unsigned short f2bf(float f) {   // fp32 -> bf16 RNE
  unsigned int u = __float_as_uint(f);
  u += 0x7FFFu + ((u >> 16) & 1u);
  return (unsigned short)(u >> 16);
}

// ---------------------------------------------------------------------------
// Histogram: counts[row[i]]++  (int atomics)
// ---------------------------------------------------------------------------
__global__ __launch_bounds__(256) void hist_kernel(
    const int* __restrict__ row, int* __restrict__ counts, int e) {
  int i = blockIdx.x * blockDim.x + threadIdx.x;
  if (i < e) atomicAdd(&counts[row[i]], 1);
}

// ---------------------------------------------------------------------------
// Scan phase 1: per-block sums of counts -> bsum[block]
// ---------------------------------------------------------------------------
__global__ __launch_bounds__(256) void block_sum_kernel(
    const int* __restrict__ counts, int* __restrict__ bsum, int n) {
  __shared__ int ws[4];
  int i = blockIdx.x * 256 + threadIdx.x;
  int lane = threadIdx.x & 63, wid = threadIdx.x >> 6;
  int v = (i < n) ? counts[i] : 0;
#pragma unroll
  for (int off = 32; off > 0; off >>= 1) v += __shfl_down(v, off, 64);
  if (lane == 0) ws[wid] = v;
  __syncthreads();
  if (threadIdx.x == 0) bsum[blockIdx.x] = ws[0] + ws[1] + ws[2] + ws[3];
}

// ---------------------------------------------------------------------------
// Scan phase 2: single block, exclusive-scan nb partials in place;
// write grand total to rowptr[NN].
// ---------------------------------------------------------------------------
__global__ __launch_bounds__(256) void scan_partials_kernel(
    int* __restrict__ bsum, int* __restrict__ rowptr, int nb, int nfull) {
  __shared__ int ws[4];
  int t = threadIdx.x;
  int lane = t & 63, wid = t >> 6;
  int v = (t < nb) ? bsum[t] : 0;
  int incl = v;
#pragma unroll
  for (int off = 1; off < 64; off <<= 1) {
    int u = __shfl_up(incl, off, 64);
    if (lane >= off) incl += u;
  }
  if (lane == 63) ws[wid] = incl;
  __syncthreads();
  int wprefix = 0;
  for (int w = 0; w < wid; ++w) wprefix += ws[w];
  incl += wprefix;
  if (t < nb) bsum[t] = incl - v;          // exclusive
  if (t == nb - 1) rowptr[nfull] = incl;   // grand total
}

// ---------------------------------------------------------------------------
// Scan phase 3: in-place exclusive scan of counts using bsum offsets.
// counts buffer then serves as the scatter write-pointer.
// ---------------------------------------------------------------------------
__global__ __launch_bounds__(256) void scan_apply_kernel(
    int* __restrict__ counts, const int* __restrict__ bsum,
    int* __restrict__ rowptr, int n) {
  __shared__ int ws[4];
  int i = blockIdx.x * 256 + threadIdx.x;
  int lane = threadIdx.x & 63, wid = threadIdx.x >> 6;
  int v = (i < n) ? counts[i] : 0;
  int incl = v;
#pragma unroll
  for (int off = 1; off < 64; off <<= 1) {
    int u = __shfl_up(incl, off, 64);
    if (lane >= off) incl += u;
  }
  if (lane == 63) ws[wid] = incl;
  __syncthreads();
  int wprefix = 0;
  for (int w = 0; w < wid; ++w) wprefix += ws[w];
  int excl = bsum[blockIdx.x] + wprefix + (incl - v);
  if (i < n) { rowptr[i] = excl; counts[i] = excl; }
}

// ---------------------------------------------------------------------------
// XCD-partitioned packed scatter (one 8B {col,val} store per edge; all
// stores to a partition's slice come from one XCD's L2 -> sectors merge).
// ---------------------------------------------------------------------------
__global__ __launch_bounds__(256) void scatter_part_kernel(
    const int* __restrict__ row, const int* __restrict__ col,
    const float* __restrict__ val, int* __restrict__ wptr,
    int2* __restrict__ pairs, int e) {
  int part = blockIdx.x & (NPART - 1);
  int q    = blockIdx.x >> 3;
  int Q    = gridDim.x >> 3;
  int lo = part * RPP, hi = lo + RPP;
  for (int i = q * 256 + threadIdx.x; i < e; i += Q * 256) {
    int r = row[i];
    if (r >= lo && r < hi) {
      int p = atomicAdd(&wptr[r], 1);
      pairs[p] = make_int2(col[i], __float_as_int(val[i]));
    }
  }
}

// ---------------------------------------------------------------------------
// CSR SpMM, D=128. One 32-lane group per row, float4 per lane.
// ---------------------------------------------------------------------------
template <bool EPI>
__global__ __launch_bounds__(256) void spmm_kernel(
    const int* __restrict__ rowptr, const int2* __restrict__ pairs,
    const float* __restrict__ dense, const float* __restrict__ bias,
    float* __restrict__ out, int n) {
  int r = blockIdx.x * 8 + (threadIdx.x >> 5);
  if (r >= n) return;
  int c4 = (threadIdx.x & 31);  // float4 index within row
  const float4* dense4 = (const float4*)dense;
  int s = rowptr[r], e = rowptr[r + 1];
  float4 acc = make_float4(0.f, 0.f, 0.f, 0.f);
  for (int j = s; j < e; ++j) {
    int2 ev = pairs[j];
    int ci = ev.x;
    float v = __int_as_float(ev.y);
    float4 d = dense4[(size_t)ci * 32 + c4];
    acc.x = fmaf(v, d.x, acc.x);
    acc.y = fmaf(v, d.y, acc.y);
    acc.z = fmaf(v, d.z, acc.z);
    acc.w = fmaf(v, d.w, acc.w);
  }
  if (EPI) {
    float4 b = ((const float4*)bias)[c4];
    acc.x = fmaxf(acc.x + b.x, 0.f);
    acc.y = fmaxf(acc.y + b.y, 0.f);
    acc.z = fmaxf(acc.z + b.z, 0.f);
    acc.w = fmaxf(acc.w + b.w, 0.f);
  }
  *(float4*)(out + (size_t)r * 128 + c4 * 4) = acc;
}

// ---------------------------------------------------------------------------
// bf16-MFMA GEMM: C[M,N] = A[M,K]@B[K,N] (+bias,relu if EPI). fp32 in/out.
// 128x128 tile, BK=32, 256 thr = 4 waves (2x2), 16x16x32 MFMA, 4x4 tiles/wave.
// LDS holds bf16 fragments in fragment-major order: MFMA-side reads are
// linear ds_read_b128 (lane i -> byte i*16), conflict-free.
// ---------------------------------------------------------------------------
template <int K, int N, bool EPI>
__global__ __launch_bounds__(256) void gemm_mfma_kernel(
    const float* __restrict__ A, const float* __restrict__ B,
    const float* __restrict__ bias, float* __restrict__ C, int M) {
  __shared__ __align__(16) unsigned short Alds[4096];  // 128x32 bf16
  __shared__ __align__(16) unsigned short Blds[4096];  // 32x128 bf16
  int tid = threadIdx.x;
  int lane = tid & 63, wid = tid >> 6;
  int wm = wid >> 1, wn = wid & 1;          // 2x2 wave grid
  int rowBase = blockIdx.x * 128;
  int colBase = blockIdx.y * 128;
  // A staging coords: thread covers (m = p*32 + tid>>3, k = (tid&7)*4)
  int kg = tid & 7, mrow = tid >> 3;
  int aquad = kg >> 1, aj0 = (kg & 1) * 4;
  // B staging coords: thread covers (col = tid&127, k = p*8 + (tid>>7)*4)
  int bn = tid & 127, kh = tid >> 7;
  int NTb = bn >> 4, nloc = bn & 15;

  f32x4 acc[4][4];
#pragma unroll
  for (int mt = 0; mt < 4; ++mt)
#pragma unroll
    for (int nt = 0; nt < 4; ++nt)
      acc[mt][nt] = (f32x4){0.f, 0.f, 0.f, 0.f};

  for (int kb = 0; kb < K; kb += 32) {
    // ---- global loads (fp32) ----
    float4 av[4];
#pragma unroll
    for (int p = 0; p < 4; ++p) {
      int r = rowBase + p * 32 + mrow;
      av[p] = (r < M) ? *(const float4*)(A + (size_t)r * K + kb + kg * 4)
                      : make_float4(0.f, 0.f, 0.f, 0.f);
    }
    float bv[4][4];
#pragma unroll
    for (int p = 0; p < 4; ++p) {
      int k = p * 8 + kh * 4;
#pragma unroll
      for (int i = 0; i < 4; ++i)
        bv[p][i] = B[(size_t)(kb + k + i) * N + colBase + bn];
    }
    __syncthreads();  // previous iteration's LDS reads complete
    // ---- convert + LDS store (fragment-major) ----
#pragma unroll
    for (int p = 0; p < 4; ++p) {
      int m = p * 32 + mrow;
      int MT = m >> 4, mloc = m & 15;
      us4 h = {f2bf(av[p].x), f2bf(av[p].y), f2bf(av[p].z), f2bf(av[p].w)};
      *(us4*)&Alds[(((MT * 4 + aquad) * 16 + mloc) << 3) + aj0] = h;
    }
#pragma unroll
    for (int p = 0; p < 4; ++p) {
      us4 h = {f2bf(bv[p][0]), f2bf(bv[p][1]), f2bf(bv[p][2]), f2bf(bv[p][3])};
      *(us4*)&Blds[(((NTb * 4 + p) * 16 + nloc) << 3) + kh * 4] = h;
    }
    __syncthreads();
    // ---- MFMA ----
    bf16x8 af[4], bf[4];
#pragma unroll
    for (int mt = 0; mt < 4; ++mt)
      af[mt] = *(bf16x8*)&Alds[(((wm * 4 + mt) * 64 + lane)) << 3];
#pragma unroll
    for (int nt = 0; nt < 4; ++nt)
      bf[nt] = *(bf16x8*)&Blds[(((wn * 4 + nt) * 64 + lane)) << 3];
#pragma unroll
    for (int mt = 0; mt < 4; ++mt)
#pragma unroll
      for (int nt = 0; nt < 4; ++nt)
        acc[mt][nt] = __builtin_amdgcn_mfma_f32_16x16x32_bf16(
            af[mt], bf[nt], acc[mt][nt], 0, 0, 0);
  }
  // ---- epilogue: C/D layout col=lane&15, row=(lane>>4)*4+i ----
  int cquad = lane >> 4, cn = lane & 15;
#pragma unroll
  for (int nt = 0; nt < 4; ++nt) {
    int col = colBase + wn * 64 + nt * 16 + cn;
    float bb = EPI ? bias[col] : 0.f;
#pragma unroll
    for (int mt = 0; mt < 4; ++mt) {
      int r0 = rowBase + wm * 64 + mt * 16 + cquad * 4;
#pragma unroll
      for (int i = 0; i < 4; ++i) {
        int r = r0 + i;
        if (r < M) {
          float o = acc[mt][nt][i];
          if (EPI) o = fmaxf(o + bb, 0.f);
          C[(size_t)r * N + col] = o;
        }
      }
    }
  }
}

// ---------------------------------------------------------------------------
extern "C" void kernel_launch(void* const* d_in, const int* in_sizes, int n_in,
                              void* d_out, int out_size, void* d_ws, size_t ws_size,
                              hipStream_t stream) {
  const float* x        = (const float*)d_in[0];
  const int*   adj_row  = (const int*)d_in[1];
  const int*   adj_col  = (const int*)d_in[2];
  const float* adj_val  = (const float*)d_in[3];
  const int*   ainv_row = (const int*)d_in[4];
  const int*   ainv_col = (const int*)d_in[5];
  const float* ainv_val = (const float*)d_in[6];
  const float* W1       = (const float*)d_in[7];
  const float* b1       = (const float*)d_in[8];
  const float* W2       = (const float*)d_in[9];
  const float* b2       = (const float*)d_in[10];

  float* out = (float*)d_out;                    // [N,512]
  float* emb = out + (size_t)NN * NFEAT;         // [N,128]

  // Workspace carve (~52 MB)
  float* H0       = (float*)d_ws;                // [N,128]; later aliased as T
  int*   rowptr_a = (int*)(H0 + (size_t)NN * HIDD);
  int*   rowptr_b = rowptr_a + 50004;
  int*   wptr_a   = rowptr_b + 50004;            // histogram -> write ptr
  int*   wptr_b   = wptr_a + 50004;
  int*   bsum_a   = wptr_b + 50004;              // NB=196 partials
  int*   bsum_b   = bsum_a + 256;
  int2*  pairs_a  = (int2*)(bsum_b + 256);       // NE packed {col,val}
  int2*  pairs_b  = pairs_a + NE;
  float* T        = H0;  // alias: H0 dead by the time T is written

  // ---- CSR build for both graphs ----
  hipMemsetAsync(wptr_a, 0, NN * sizeof(int), stream);
  hipMemsetAsync(wptr_b, 0, NN * sizeof(int), stream);
  hist_kernel<<<NE / 256, 256, 0, stream>>>(adj_row, wptr_a, NE);
  hist_kernel<<<NE / 256, 256, 0, stream>>>(ainv_row, wptr_b, NE);
  block_sum_kernel<<<NB, 256, 0, stream>>>(wptr_a, bsum_a, NN);
  block_sum_kernel<<<NB, 256, 0, stream>>>(wptr_b, bsum_b, NN);
  scan_partials_kernel<<<1, 256, 0, stream>>>(bsum_a, rowptr_a, NB, NN);
  scan_partials_kernel<<<1, 256, 0, stream>>>(bsum_b, rowptr_b, NB, NN);
  scan_apply_kernel<<<NB, 256, 0, stream>>>(wptr_a, bsum_a, rowptr_a, NN);
  scan_apply_kernel<<<NB, 256, 0, stream>>>(wptr_b, bsum_b, rowptr_b, NN);
  scatter_part_kernel<<<2048, 256, 0, stream>>>(adj_row, adj_col, adj_val,
                                                wptr_a, pairs_a, NE);
  scatter_part_kernel<<<2048, 256, 0, stream>>>(ainv_row, ainv_col, ainv_val,
                                                wptr_b, pairs_b, NE);

  // ---- H0 = X @ W1 (bf16 MFMA) ----
  gemm_mfma_kernel<NFEAT, HIDD, false>
      <<<dim3((NN + 127) / 128, 1), 256, 0, stream>>>(x, W1, nullptr, H0, NN);

  // ---- emb = relu(A @ H0 + b1) ----
  spmm_kernel<true><<<(NN + 7) / 8, 256, 0, stream>>>(
      rowptr_a, pairs_a, H0, b1, emb, NN);

  // ---- T = A_inv @ emb  (reassociated: (A_inv @ h) @ W2) ----
  spmm_kernel<false><<<(NN + 7) / 8, 256, 0, stream>>>(
      rowptr_b, pairs_b, emb, nullptr, T, NN);

  // ---- out = relu(T @ W2 + b2) (bf16 MFMA) ----
  gemm_mfma_kernel<HIDD, NFEAT, true>
      <<<dim3((NN + 127) / 128, 4), 256, 0, stream>>>(T, W2, b2, out, NN);
}